// Round 1
// baseline (1703.380 us; speedup 1.0000x reference)
//
#include <hip/hip_runtime.h>

// Peeling propagation on bipartite graph.
// V=1e6 variables, F=4.2e6 functions, K=3 edges/function (edge e -> function e/3,
// guaranteed by setup: fidx = repeat(arange(F), 3)). T=5 iterations.
// Output: deg (V floats) lives directly in d_out.

static constexpr int Vn = 1000000;
static constexpr int Fn = 4200000;
static constexpr int Tn = 5;

__global__ void k_init_v(const float* __restrict__ active_variables,
                         float* __restrict__ deg, float* __restrict__ sdeg,
                         float* __restrict__ tmp_deg, float* __restrict__ tmp_sdeg,
                         float* __restrict__ av) {
    int v = blockIdx.x * blockDim.x + threadIdx.x;
    if (v < Vn) {
        deg[v] = 0.0f;
        sdeg[v] = 0.0f;
        tmp_deg[v] = 0.0f;
        tmp_sdeg[v] = 0.0f;
        av[v] = active_variables[v];
    }
}

// Initial variable_degree / signed_variable_degree via scatter-atomics.
// Function f owns edges 3f..3f+2 (contiguous), so no F-side atomics ever.
__global__ void k_init_f(const int* __restrict__ vidx, const float* __restrict__ ef,
                         const float* __restrict__ active_functions,
                         float* __restrict__ af,
                         float* __restrict__ deg, float* __restrict__ sdeg) {
    int f = blockIdx.x * blockDim.x + threadIdx.x;
    if (f < Fn) {
        float a = active_functions[f];
        af[f] = a;
        if (a != 0.0f) {
            int e0 = 3 * f;
            #pragma unroll
            for (int j = 0; j < 3; ++j) {
                int v = vidx[e0 + j];
                atomicAdd(&deg[v], a);
                atomicAdd(&sdeg[v], ef[e0 + j] * a);
            }
        }
    }
}

__global__ void k_single_v(const float* __restrict__ deg, const float* __restrict__ sdeg,
                           const float* __restrict__ av, float* __restrict__ single_v) {
    int v = blockIdx.x * blockDim.x + threadIdx.x;
    if (v < Vn) {
        single_v[v] = (deg[v] == fabsf(sdeg[v])) ? av[v] : 0.0f;
    }
}

// Per-function: single_f = (sum of 3 gathered single_v > 0) * af;
// sparse af update + sparse scatter of single_f (and ef*single_f) into tmp arrays.
// ~99% of functions take no atomics (single_v fires for ~0.4% of variables).
__global__ void k_funcs(const int* __restrict__ vidx, const float* __restrict__ ef,
                        const float* __restrict__ single_v,
                        float* __restrict__ af,
                        float* __restrict__ tmp_deg, float* __restrict__ tmp_sdeg) {
    int f = blockIdx.x * blockDim.x + threadIdx.x;
    if (f < Fn) {
        int e0 = 3 * f;
        int v0 = vidx[e0], v1 = vidx[e0 + 1], v2 = vidx[e0 + 2];
        float s = single_v[v0] + single_v[v1] + single_v[v2];
        if (s > 0.0f) {
            float a = af[f];
            if (a != 0.0f) {
                float sf = a;                 // single_f = 1{s>0} * af
                af[f] = a * (1.0f - sf);      // af *= (1 - single_f)
                atomicAdd(&tmp_deg[v0], sf);
                atomicAdd(&tmp_deg[v1], sf);
                atomicAdd(&tmp_deg[v2], sf);
                atomicAdd(&tmp_sdeg[v0], ef[e0] * sf);
                atomicAdd(&tmp_sdeg[v1], ef[e0 + 1] * sf);
                atomicAdd(&tmp_sdeg[v2], ef[e0 + 2] * sf);
            }
        }
    }
}

// Per-variable update, fused with computation of NEXT iteration's single_v:
//   deg  -= tmp_deg  * av_old;  sdeg -= tmp_sdeg * av_old;
//   av    = av_old * (1 - single_v);
//   single_v_next = (deg' == |sdeg'|) * av'
// Also zeroes tmp arrays for the next iteration (sparse writes).
__global__ void k_update(float* __restrict__ deg, float* __restrict__ sdeg,
                         float* __restrict__ av, float* __restrict__ single_v,
                         float* __restrict__ tmp_deg, float* __restrict__ tmp_sdeg) {
    int v = blockIdx.x * blockDim.x + threadIdx.x;
    if (v < Vn) {
        float a = av[v];
        float d = deg[v], s = sdeg[v];
        float td = tmp_deg[v], ts = tmp_sdeg[v];
        if (td != 0.0f || ts != 0.0f) {
            d -= td * a;
            s -= ts * a;
            deg[v] = d;
            sdeg[v] = s;
            tmp_deg[v] = 0.0f;
            tmp_sdeg[v] = 0.0f;
        }
        float sv = single_v[v];
        if (sv != 0.0f) {
            a = a * (1.0f - sv);
            av[v] = a;
        }
        single_v[v] = (d == fabsf(s)) ? a : 0.0f;
    }
}

extern "C" void kernel_launch(void* const* d_in, const int* in_sizes, int n_in,
                              void* d_out, int out_size, void* d_ws, size_t ws_size,
                              hipStream_t stream) {
    const int*   graph_map        = (const int*)d_in[0];   // [2, E]: row0 = vidx, row1 = fidx (= e/3, structural)
    const float* edge_feature     = (const float*)d_in[1]; // [E], values +-1
    const float* active_variables = (const float*)d_in[2]; // [V]
    const float* active_functions = (const float*)d_in[3]; // [F]

    const int* vidx = graph_map;  // first E entries

    float* deg = (float*)d_out;   // output lives here
    float* ws  = (float*)d_ws;
    float* sdeg     = ws;
    float* tmp_deg  = ws + (size_t)Vn;
    float* tmp_sdeg = ws + 2 * (size_t)Vn;
    float* single_v = ws + 3 * (size_t)Vn;
    float* av       = ws + 4 * (size_t)Vn;
    float* af       = ws + 5 * (size_t)Vn;  // F floats

    const int BS = 256;
    const int gV = (Vn + BS - 1) / BS;
    const int gF = (Fn + BS - 1) / BS;

    k_init_v<<<gV, BS, 0, stream>>>(active_variables, deg, sdeg, tmp_deg, tmp_sdeg, av);
    k_init_f<<<gF, BS, 0, stream>>>(vidx, edge_feature, active_functions, af, deg, sdeg);
    k_single_v<<<gV, BS, 0, stream>>>(deg, sdeg, av, single_v);
    for (int t = 0; t < Tn; ++t) {
        k_funcs<<<gF, BS, 0, stream>>>(vidx, edge_feature, single_v, af, tmp_deg, tmp_sdeg);
        k_update<<<gV, BS, 0, stream>>>(deg, sdeg, av, single_v, tmp_deg, tmp_sdeg);
    }
}

// Round 2
// 973.082 us; speedup vs baseline: 1.7505x; 1.7505x over previous
//
#include <hip/hip_runtime.h>

// Peeling propagation on bipartite graph.
// V=1e6 variables, F=4.2e6 functions, K=3 edges/function (edge e -> function e/3,
// structural: fidx = repeat(arange(F), 3)). T=5 iterations.
// Output: deg (V floats) lives directly in d_out.
//
// R1 change: pack (count, #positive-sign) into ONE u32 atomic per edge instead of
// two f32 atomics (deg, sdeg). Valid because af/single_f in {0,1} here, so
// deg = count and sdeg = 2*pos - count. lo16 (pos) can't carry into hi16 (count).
// Halves the 25.2M-atomic init scatter that dominated R0 (1205 of 1703 us).

static constexpr int Vn = 1000000;
static constexpr int Fn = 4200000;
static constexpr int Tn = 5;

__global__ void k_init_v(unsigned int* __restrict__ packed,
                         unsigned int* __restrict__ tmp_packed,
                         const float* __restrict__ active_variables,
                         float* __restrict__ av) {
    int v = blockIdx.x * blockDim.x + threadIdx.x;
    if (v < Vn) {
        packed[v] = 0u;
        tmp_packed[v] = 0u;
        av[v] = active_variables[v];
    }
}

// Initial degree scatter: one u32 atomic per edge.
// value = (1<<16) | (ef > 0); deg = hi16, sdeg = 2*lo16 - hi16.
__global__ void k_init_f(const int* __restrict__ vidx, const float* __restrict__ ef,
                         const float* __restrict__ active_functions,
                         float* __restrict__ af,
                         unsigned int* __restrict__ packed) {
    int f = blockIdx.x * blockDim.x + threadIdx.x;
    if (f < Fn) {
        float a = active_functions[f];
        af[f] = a;
        if (a != 0.0f) {              // a == 1.0 when active (binary mask input)
            int e0 = 3 * f;
            #pragma unroll
            for (int j = 0; j < 3; ++j) {
                int v = vidx[e0 + j];
                unsigned int inc = 0x10000u | (ef[e0 + j] > 0.0f ? 1u : 0u);
                atomicAdd(&packed[v], inc);
            }
        }
    }
}

// Decode packed -> float deg/sdeg, and compute initial single_v.
__global__ void k_decode(const unsigned int* __restrict__ packed,
                         const float* __restrict__ av,
                         float* __restrict__ deg, float* __restrict__ sdeg,
                         float* __restrict__ single_v) {
    int v = blockIdx.x * blockDim.x + threadIdx.x;
    if (v < Vn) {
        unsigned int p = packed[v];
        int c = (int)(p >> 16);
        int pos = (int)(p & 0xFFFFu);
        float d = (float)c;
        float s = (float)(2 * pos - c);
        deg[v] = d;
        sdeg[v] = s;
        single_v[v] = (d == fabsf(s)) ? av[v] : 0.0f;
    }
}

// Per-function: single_f = (sum of 3 gathered single_v > 0) * af;
// sparse af update + ONE packed atomic per edge into tmp_packed.
// ~99% of functions take no atomics (single_v fires for ~0.4% of variables).
__global__ void k_funcs(const int* __restrict__ vidx, const float* __restrict__ ef,
                        const float* __restrict__ single_v,
                        float* __restrict__ af,
                        unsigned int* __restrict__ tmp_packed) {
    int f = blockIdx.x * blockDim.x + threadIdx.x;
    if (f < Fn) {
        int e0 = 3 * f;
        int v0 = vidx[e0], v1 = vidx[e0 + 1], v2 = vidx[e0 + 2];
        float s = single_v[v0] + single_v[v1] + single_v[v2];
        if (s > 0.0f) {
            float a = af[f];
            if (a != 0.0f) {          // single_f = af (== 1), function deactivates
                af[f] = 0.0f;
                atomicAdd(&tmp_packed[v0], 0x10000u | (ef[e0]     > 0.0f ? 1u : 0u));
                atomicAdd(&tmp_packed[v1], 0x10000u | (ef[e0 + 1] > 0.0f ? 1u : 0u));
                atomicAdd(&tmp_packed[v2], 0x10000u | (ef[e0 + 2] > 0.0f ? 1u : 0u));
            }
        }
    }
}

// Per-variable update, fused with NEXT iteration's single_v:
//   deg  -= c * av_old;  sdeg -= (2p - c) * av_old;
//   av    = av_old * (1 - single_v);
//   single_v_next = (deg' == |sdeg'|) * av'
// Zeroes tmp_packed for the next iteration (sparse writes).
__global__ void k_update(float* __restrict__ deg, float* __restrict__ sdeg,
                         float* __restrict__ av, float* __restrict__ single_v,
                         unsigned int* __restrict__ tmp_packed) {
    int v = blockIdx.x * blockDim.x + threadIdx.x;
    if (v < Vn) {
        float a = av[v];
        float d = deg[v], s = sdeg[v];
        unsigned int tp = tmp_packed[v];
        if (tp != 0u) {
            int c = (int)(tp >> 16);
            int pos = (int)(tp & 0xFFFFu);
            d -= (float)c * a;
            s -= (float)(2 * pos - c) * a;
            deg[v] = d;
            sdeg[v] = s;
            tmp_packed[v] = 0u;
        }
        float sv = single_v[v];
        if (sv != 0.0f) {
            a = a * (1.0f - sv);
            av[v] = a;
        }
        single_v[v] = (d == fabsf(s)) ? a : 0.0f;
    }
}

extern "C" void kernel_launch(void* const* d_in, const int* in_sizes, int n_in,
                              void* d_out, int out_size, void* d_ws, size_t ws_size,
                              hipStream_t stream) {
    const int*   graph_map        = (const int*)d_in[0];   // [2, E]: row0 = vidx
    const float* edge_feature     = (const float*)d_in[1]; // [E], values +-1
    const float* active_variables = (const float*)d_in[2]; // [V]
    const float* active_functions = (const float*)d_in[3]; // [F]

    const int* vidx = graph_map;  // first E entries

    float* deg = (float*)d_out;   // output lives here
    char* ws = (char*)d_ws;
    unsigned int* packed     = (unsigned int*)ws;                         // V u32
    unsigned int* tmp_packed = (unsigned int*)(ws + 4ull * Vn);           // V u32
    float* sdeg     = (float*)(ws + 8ull * Vn);                           // V f32
    float* single_v = (float*)(ws + 12ull * Vn);                          // V f32
    float* av       = (float*)(ws + 16ull * Vn);                          // V f32
    float* af       = (float*)(ws + 20ull * Vn);                          // F f32

    const int BS = 256;
    const int gV = (Vn + BS - 1) / BS;
    const int gF = (Fn + BS - 1) / BS;

    k_init_v<<<gV, BS, 0, stream>>>(packed, tmp_packed, active_variables, av);
    k_init_f<<<gF, BS, 0, stream>>>(vidx, edge_feature, active_functions, af, packed);
    k_decode<<<gV, BS, 0, stream>>>(packed, av, deg, sdeg, single_v);
    for (int t = 0; t < Tn; ++t) {
        k_funcs<<<gF, BS, 0, stream>>>(vidx, edge_feature, single_v, af, tmp_packed);
        k_update<<<gV, BS, 0, stream>>>(deg, sdeg, av, single_v, tmp_packed);
    }
}

// Round 3
// 862.759 us; speedup vs baseline: 1.9743x; 1.1279x over previous
//
#include <hip/hip_runtime.h>

// Peeling propagation on bipartite graph.
// V=1e6 variables, F=4.2e6 functions, K=3 edges/function (edge e -> function e/3,
// structural: fidx = repeat(arange(F), 3)). T=5 iterations.
// Output: deg (V floats) lives directly in d_out.
//
// R2 change: replace the 12.6M-global-atomic init scatter (475 us, atomic-op bound
// at ~26 G/s with 32B write-through per op) with a counting sort by variable bin
// (977 bins x 1024 vars) + per-bin LDS accumulation. Only LDS atomics remain.
// Iteration path (k_funcs/k_update) unchanged from R1.

static constexpr int Vn = 1000000;
static constexpr int Fn = 4200000;
static constexpr int En = 3 * Fn;   // 12,600,000 edges
static constexpr int Tn = 5;

static constexpr int BIN_BITS = 10;                         // 1024 vars per bin
static constexpr int BIN_SIZE = 1 << BIN_BITS;
static constexpr int NB = (Vn + BIN_SIZE - 1) >> BIN_BITS;  // 977 bins
static constexpr int SBLK = 256;                            // blocks in hist/scatter
static constexpr int EPB = (En + SBLK - 1) / SBLK;          // 49219 edges per block

// ---- init: per-variable state ----
__global__ void k_init_v(unsigned int* __restrict__ tmp_packed,
                         const float* __restrict__ active_variables,
                         float* __restrict__ av) {
    int v = blockIdx.x * blockDim.x + threadIdx.x;
    if (v < Vn) {
        tmp_packed[v] = 0u;
        av[v] = active_variables[v];
    }
}

__global__ void k_init_af(const float* __restrict__ active_functions,
                          float* __restrict__ af) {
    int f = blockIdx.x * blockDim.x + threadIdx.x;
    if (f < Fn) af[f] = active_functions[f];
}

// ---- S1: per-block histogram over variable bins (LDS atomics, plain stores out) ----
__global__ void k_hist(const int* __restrict__ vidx, unsigned int* __restrict__ counts) {
    __shared__ unsigned int h[NB];
    for (int i = threadIdx.x; i < NB; i += blockDim.x) h[i] = 0u;
    __syncthreads();
    int base = blockIdx.x * EPB;
    int end = min(En, base + EPB);
    for (int e = base + threadIdx.x; e < end; e += blockDim.x) {
        int v = vidx[e];
        atomicAdd(&h[v >> BIN_BITS], 1u);
    }
    __syncthreads();
    for (int i = threadIdx.x; i < NB; i += blockDim.x)
        counts[(size_t)i * SBLK + blockIdx.x] = h[i];   // counts[bin][block], contiguous per bin
}

// ---- S2a: per-bin exclusive scan over the 256 blocks; emit bin totals ----
__global__ void k_colscan(unsigned int* __restrict__ counts, unsigned int* __restrict__ bin_total) {
    int b = blockIdx.x * blockDim.x + threadIdx.x;
    if (b < NB) {
        unsigned int run = 0u;
        unsigned int* col = counts + (size_t)b * SBLK;
        for (int k = 0; k < SBLK; ++k) { unsigned int t = col[k]; col[k] = run; run += t; }
        bin_total[b] = run;
    }
}

// ---- S2b: exclusive scan over bins -> bin_start[0..NB] ----
__global__ void k_binscan(const unsigned int* __restrict__ bin_total,
                          unsigned int* __restrict__ bin_start) {
    __shared__ unsigned int s[1024];
    int i = threadIdx.x;  // blockDim = 1024
    s[i] = (i < NB) ? bin_total[i] : 0u;
    __syncthreads();
    for (int off = 1; off < 1024; off <<= 1) {
        unsigned int add = (i >= off) ? s[i - off] : 0u;
        __syncthreads();
        s[i] += add;
        __syncthreads();
    }
    if (i < NB) bin_start[i + 1] = s[i];
    if (i == 0) bin_start[0] = 0u;
}

// ---- S3: scatter edges into bin-sorted order as u16 (v_in_bin | sign<<10) ----
__global__ void k_scatter(const int* __restrict__ vidx, const float* __restrict__ ef,
                          const unsigned int* __restrict__ counts,
                          const unsigned int* __restrict__ bin_start,
                          unsigned short* __restrict__ sorted) {
    __shared__ unsigned int cur[NB];
    for (int i = threadIdx.x; i < NB; i += blockDim.x)
        cur[i] = bin_start[i] + counts[(size_t)i * SBLK + blockIdx.x];
    __syncthreads();
    int base = blockIdx.x * EPB;
    int end = min(En, base + EPB);
    for (int e = base + threadIdx.x; e < end; e += blockDim.x) {
        int v = vidx[e];
        unsigned int sign = ef[e] > 0.0f ? 1u : 0u;
        unsigned int slot = atomicAdd(&cur[v >> BIN_BITS], 1u);   // LDS atomic
        sorted[slot] = (unsigned short)((v & (BIN_SIZE - 1)) | (sign << BIN_BITS));
    }
}

// ---- S4: per-bin LDS accumulate + decode to deg/sdeg/single_v (fused k_decode) ----
__global__ void k_accum(const unsigned short* __restrict__ sorted,
                        const unsigned int* __restrict__ bin_start,
                        const float* __restrict__ active_variables,
                        float* __restrict__ deg, float* __restrict__ sdeg,
                        float* __restrict__ single_v) {
    __shared__ unsigned int acc[BIN_SIZE];
    int b = blockIdx.x;
    for (int i = threadIdx.x; i < BIN_SIZE; i += blockDim.x) acc[i] = 0u;
    __syncthreads();
    int s0 = (int)bin_start[b], s1 = (int)bin_start[b + 1];
    for (int e = s0 + threadIdx.x; e < s1; e += blockDim.x) {
        unsigned int p = sorted[e];
        atomicAdd(&acc[p & (BIN_SIZE - 1)], 0x10000u | (p >> BIN_BITS));  // LDS atomic
    }
    __syncthreads();
    int vbase = b << BIN_BITS;
    for (int i = threadIdx.x; i < BIN_SIZE; i += blockDim.x) {
        int v = vbase + i;
        if (v < Vn) {
            unsigned int p = acc[i];
            int c = (int)(p >> 16);
            int pos = (int)(p & 0xFFFFu);
            float d = (float)c;
            float s = (float)(2 * pos - c);
            deg[v] = d;
            sdeg[v] = s;
            single_v[v] = (d == fabsf(s)) ? active_variables[v] : 0.0f;
        }
    }
}

// ---- iteration kernels: unchanged from R1 ----
__global__ void k_funcs(const int* __restrict__ vidx, const float* __restrict__ ef,
                        const float* __restrict__ single_v,
                        float* __restrict__ af,
                        unsigned int* __restrict__ tmp_packed) {
    int f = blockIdx.x * blockDim.x + threadIdx.x;
    if (f < Fn) {
        int e0 = 3 * f;
        int v0 = vidx[e0], v1 = vidx[e0 + 1], v2 = vidx[e0 + 2];
        float s = single_v[v0] + single_v[v1] + single_v[v2];
        if (s > 0.0f) {
            float a = af[f];
            if (a != 0.0f) {          // single_f = af (== 1), function deactivates
                af[f] = 0.0f;
                atomicAdd(&tmp_packed[v0], 0x10000u | (ef[e0]     > 0.0f ? 1u : 0u));
                atomicAdd(&tmp_packed[v1], 0x10000u | (ef[e0 + 1] > 0.0f ? 1u : 0u));
                atomicAdd(&tmp_packed[v2], 0x10000u | (ef[e0 + 2] > 0.0f ? 1u : 0u));
            }
        }
    }
}

__global__ void k_update(float* __restrict__ deg, float* __restrict__ sdeg,
                         float* __restrict__ av, float* __restrict__ single_v,
                         unsigned int* __restrict__ tmp_packed) {
    int v = blockIdx.x * blockDim.x + threadIdx.x;
    if (v < Vn) {
        float a = av[v];
        float d = deg[v], s = sdeg[v];
        unsigned int tp = tmp_packed[v];
        if (tp != 0u) {
            int c = (int)(tp >> 16);
            int pos = (int)(tp & 0xFFFFu);
            d -= (float)c * a;
            s -= (float)(2 * pos - c) * a;
            deg[v] = d;
            sdeg[v] = s;
            tmp_packed[v] = 0u;
        }
        float sv = single_v[v];
        if (sv != 0.0f) {
            a = a * (1.0f - sv);
            av[v] = a;
        }
        single_v[v] = (d == fabsf(s)) ? a : 0.0f;
    }
}

extern "C" void kernel_launch(void* const* d_in, const int* in_sizes, int n_in,
                              void* d_out, int out_size, void* d_ws, size_t ws_size,
                              hipStream_t stream) {
    const int*   graph_map        = (const int*)d_in[0];   // [2, E]: row0 = vidx
    const float* edge_feature     = (const float*)d_in[1]; // [E], values +-1
    const float* active_variables = (const float*)d_in[2]; // [V]
    const float* active_functions = (const float*)d_in[3]; // [F]

    const int* vidx = graph_map;  // first E entries

    float* deg = (float*)d_out;   // output lives here
    char* ws = (char*)d_ws;
    size_t off = 0;
    unsigned int* tmp_packed = (unsigned int*)(ws + off); off += 4ull * Vn;          // 4.0 MB
    float* sdeg      = (float*)(ws + off); off += 4ull * Vn;                          // 4.0 MB
    float* single_v  = (float*)(ws + off); off += 4ull * Vn;                          // 4.0 MB
    float* av        = (float*)(ws + off); off += 4ull * Vn;                          // 4.0 MB
    float* af        = (float*)(ws + off); off += 4ull * Fn;                          // 16.8 MB
    unsigned int* counts    = (unsigned int*)(ws + off); off += 4ull * NB * SBLK;     // 1.0 MB
    unsigned int* bin_total = (unsigned int*)(ws + off); off += 4ull * NB;            // 3.9 KB
    unsigned int* bin_start = (unsigned int*)(ws + off); off += 4ull * (NB + 1);      // 3.9 KB
    unsigned short* sorted  = (unsigned short*)(ws + off); off += 2ull * En;          // 25.2 MB
    // total ~59.1 MB

    const int BS = 256;
    const int gV = (Vn + BS - 1) / BS;
    const int gF = (Fn + BS - 1) / BS;

    k_init_v<<<gV, BS, 0, stream>>>(tmp_packed, active_variables, av);
    k_init_af<<<gF, BS, 0, stream>>>(active_functions, af);
    k_hist<<<SBLK, BS, 0, stream>>>(vidx, counts);
    k_colscan<<<(NB + BS - 1) / BS, BS, 0, stream>>>(counts, bin_total);
    k_binscan<<<1, 1024, 0, stream>>>(bin_total, bin_start);
    k_scatter<<<SBLK, BS, 0, stream>>>(vidx, edge_feature, counts, bin_start, sorted);
    k_accum<<<NB, BS, 0, stream>>>(sorted, bin_start, active_variables, deg, sdeg, single_v);
    for (int t = 0; t < Tn; ++t) {
        k_funcs<<<gF, BS, 0, stream>>>(vidx, edge_feature, single_v, af, tmp_packed);
        k_update<<<gV, BS, 0, stream>>>(deg, sdeg, av, single_v, tmp_packed);
    }
}

// Round 4
// 556.514 us; speedup vs baseline: 3.0608x; 1.5503x over previous
//
#include <hip/hip_runtime.h>

// Peeling propagation on bipartite graph. V=1e6, F=4.2e6, K=3 (edge e -> function e/3).
// T=5. Output: deg (V floats) in d_out.
//
// R3 redesign:
//  * k_pack_sort (fused pack+hist+local-scan+scatter, 1024 blocks):
//    - builds gpack[f] = v0|v1<<20|v2<<40|signs<<60|active<<63 (u64, read every iter)
//    - counting-sorts edges by 2048-var bin into BLOCK-PRIVATE regions (kills the
//      cross-XCD false-sharing that made R2's scatter write 269 MB for 25 MB payload)
//  * k_accum: per-bin LDS accumulate -> packed[v] = count<<16|positives, plus av/sv bitmasks.
//  * iterations: gpack stream (33.6 MB) + 125 KB single_v bitmask gathers + sparse atomics.
//  * state stays integer-packed; final k_out decodes deg to float.

static constexpr int Vn = 1000000;          // 64 * 15625, bitmask-friendly
static constexpr int Fn = 4200000;
static constexpr int Tn = 5;

static constexpr int SBLK = 1024;                         // sort blocks
static constexpr int FPB  = (Fn + SBLK - 1) / SBLK;       // 4102 functions/block
static constexpr int BIN_BITS = 11;                       // 2048 vars/bin
static constexpr int BIN_SIZE = 1 << BIN_BITS;
static constexpr int NB  = (Vn + BIN_SIZE - 1) >> BIN_BITS;  // 489 bins
static constexpr int NBP = 512;                           // padded for scan
static constexpr int RCAP = 3 * FPB;                      // 12306 max entries/block
static constexpr int RSTRIDE = (RCAP + 63) & ~63;         // 12352 entries -> 128B-aligned regions
static constexpr int OROW = NBP;                          // offs row stride (u16 entries)

// ---- fused pack + histogram + block-local scan + block-private scatter ----
__global__ __launch_bounds__(512) void k_pack_sort(
    const int* __restrict__ vidx, const float* __restrict__ ef,
    const float* __restrict__ afunc,
    unsigned long long* __restrict__ gpack,
    unsigned short* __restrict__ offs,      // [SBLK][OROW] exclusive bin offsets per block
    unsigned short* __restrict__ sorted)    // [SBLK][RSTRIDE] block-private regions
{
    __shared__ unsigned long long gl[FPB];
    __shared__ unsigned int hist[NBP];
    __shared__ unsigned int scanA[NBP];
    __shared__ unsigned int cur[NBP];

    const int k = blockIdx.x;
    const int f0 = k * FPB;
    const int f1 = (f0 + FPB < Fn) ? (f0 + FPB) : Fn;
    const int n = f1 - f0;

    for (int i = threadIdx.x; i < NBP; i += 512) hist[i] = 0u;
    __syncthreads();

    // pass 1: read vidx/ef/afunc ONCE, build gpack (LDS + global), histogram bins
    for (int i = threadIdx.x; i < n; i += 512) {
        int f = f0 + i;
        int e0 = 3 * f;
        int v0 = vidx[e0], v1 = vidx[e0 + 1], v2 = vidx[e0 + 2];
        unsigned int s0 = ef[e0]     > 0.0f ? 1u : 0u;
        unsigned int s1 = ef[e0 + 1] > 0.0f ? 1u : 0u;
        unsigned int s2 = ef[e0 + 2] > 0.0f ? 1u : 0u;
        unsigned int act = afunc[f] != 0.0f ? 1u : 0u;
        unsigned long long g = (unsigned long long)(unsigned int)v0
                             | ((unsigned long long)(unsigned int)v1 << 20)
                             | ((unsigned long long)(unsigned int)v2 << 40)
                             | ((unsigned long long)s0 << 60)
                             | ((unsigned long long)s1 << 61)
                             | ((unsigned long long)s2 << 62)
                             | ((unsigned long long)act << 63);
        gl[i] = g;
        gpack[f] = g;
        if (act) {
            atomicAdd(&hist[v0 >> BIN_BITS], 1u);
            atomicAdd(&hist[v1 >> BIN_BITS], 1u);
            atomicAdd(&hist[v2 >> BIN_BITS], 1u);
        }
    }
    __syncthreads();

    // block-local Hillis-Steele inclusive scan over NBP=512 bins (512 threads)
    {
        int i = threadIdx.x;
        scanA[i] = hist[i];
        __syncthreads();
        for (int off = 1; off < NBP; off <<= 1) {
            unsigned int add = (i >= off) ? scanA[i - off] : 0u;
            __syncthreads();
            scanA[i] += add;
            __syncthreads();
        }
        unsigned int excl = (i == 0) ? 0u : scanA[i - 1];
        cur[i] = excl;
        if (i <= NB) offs[(size_t)k * OROW + i] = (unsigned short)excl;  // offs[NB] = total
    }
    __syncthreads();

    // pass 2: scatter edges (from LDS) into block-private region
    const unsigned int rbase = (unsigned int)k * (unsigned int)RSTRIDE;
    for (int i = threadIdx.x; i < n; i += 512) {
        unsigned long long g = gl[i];
        if ((long long)g < 0) {  // active
            int v0 = (int)(g & 0xFFFFFu);
            int v1 = (int)((g >> 20) & 0xFFFFFu);
            int v2 = (int)((g >> 40) & 0xFFFFFu);
            unsigned int sl0 = atomicAdd(&cur[v0 >> BIN_BITS], 1u);
            sorted[rbase + sl0] = (unsigned short)((v0 & (BIN_SIZE - 1)) | ((unsigned int)((g >> 60) & 1u) << BIN_BITS));
            unsigned int sl1 = atomicAdd(&cur[v1 >> BIN_BITS], 1u);
            sorted[rbase + sl1] = (unsigned short)((v1 & (BIN_SIZE - 1)) | ((unsigned int)((g >> 61) & 1u) << BIN_BITS));
            unsigned int sl2 = atomicAdd(&cur[v2 >> BIN_BITS], 1u);
            sorted[rbase + sl2] = (unsigned short)((v2 & (BIN_SIZE - 1)) | ((unsigned int)((g >> 62) & 1u) << BIN_BITS));
        }
    }
}

// ---- per-bin accumulate + decode: packed[v], av/sv bitmasks ----
__global__ __launch_bounds__(512) void k_accum(
    const unsigned short* __restrict__ offs,
    const unsigned short* __restrict__ sorted,
    const float* __restrict__ avars,
    unsigned int* __restrict__ packed,
    unsigned long long* __restrict__ avm,
    unsigned long long* __restrict__ svm)
{
    __shared__ unsigned int acc[BIN_SIZE];
    const int b = blockIdx.x;
    for (int i = threadIdx.x; i < BIN_SIZE; i += 512) acc[i] = 0u;
    __syncthreads();
    for (int k = threadIdx.x; k < SBLK; k += 512) {
        const unsigned short* orow = offs + (size_t)k * OROW;
        int s0 = orow[b], s1 = orow[b + 1];
        const unsigned short* seg = sorted + (size_t)k * RSTRIDE;
        for (int e = s0; e < s1; ++e) {
            unsigned int p = seg[e];
            atomicAdd(&acc[p & (BIN_SIZE - 1)], 0x10000u | (p >> BIN_BITS));
        }
    }
    __syncthreads();
    const int vbase = b << BIN_BITS;
    for (int i = threadIdx.x; i < BIN_SIZE; i += 512) {
        int v = vbase + i;
        bool valid = v < Vn;
        unsigned int p = valid ? acc[i] : 0u;
        bool av = valid && (avars[v] != 0.0f);
        unsigned int c = p >> 16, pos = p & 0xFFFFu;
        bool sv = av && (pos == 0u || pos == c);   // deg == |sdeg|
        unsigned long long avb = __ballot(av);
        unsigned long long svb = __ballot(sv);
        if (valid) packed[v] = p;
        if ((threadIdx.x & 63) == 0 && valid) {
            avm[v >> 6] = avb;
            svm[v >> 6] = svb;
        }
    }
}

__global__ void k_zero_tmp(unsigned int* __restrict__ tmp) {
    int v = blockIdx.x * blockDim.x + threadIdx.x;
    if (v < Vn) tmp[v] = 0u;
}

// ---- iteration: function side. gpack stream + 3 bitmask gathers; sparse fire. ----
__global__ void k_funcs(unsigned long long* __restrict__ gpack,
                        const unsigned int* __restrict__ svm32,
                        unsigned int* __restrict__ tmp)
{
    int f = blockIdx.x * blockDim.x + threadIdx.x;
    if (f >= Fn) return;
    unsigned long long g = gpack[f];
    if ((long long)g >= 0) return;               // inactive (bit63 clear)
    unsigned int v0 = (unsigned int)(g & 0xFFFFFu);
    unsigned int v1 = (unsigned int)((g >> 20) & 0xFFFFFu);
    unsigned int v2 = (unsigned int)((g >> 40) & 0xFFFFFu);
    unsigned int hit = ((svm32[v0 >> 5] >> (v0 & 31u)) |
                        (svm32[v1 >> 5] >> (v1 & 31u)) |
                        (svm32[v2 >> 5] >> (v2 & 31u))) & 1u;
    if (!hit) return;
    gpack[f] = g & ~(1ull << 63);                // function deactivates (single_f = 1)
    atomicAdd(&tmp[v0], 0x10000u | (unsigned int)((g >> 60) & 1u));
    atomicAdd(&tmp[v1], 0x10000u | (unsigned int)((g >> 61) & 1u));
    atomicAdd(&tmp[v2], 0x10000u | (unsigned int)((g >> 62) & 1u));
}

// ---- iteration: variable side. packed -= tmp (av-gated), refresh av/sv bitmasks. ----
__global__ void k_update(unsigned int* __restrict__ packed,
                         unsigned int* __restrict__ tmp,
                         unsigned long long* __restrict__ avm,
                         unsigned long long* __restrict__ svm)
{
    int v = blockIdx.x * blockDim.x + threadIdx.x;
    int lane = threadIdx.x & 63;
    bool valid = v < Vn;
    unsigned long long avw = 0ull, svw = 0ull;
    if (valid) { avw = avm[v >> 6]; svw = svm[v >> 6]; }   // wave-broadcast loads
    bool av_old = valid && ((avw >> lane) & 1ull);
    bool sv     = valid && ((svw >> lane) & 1ull);
    bool av_new = av_old && !sv;                            // av *= (1 - single_v)
    unsigned int p = 0u;
    if (valid) {
        unsigned int tp = tmp[v];
        p = packed[v];
        if (tp != 0u) {
            if (av_old) { p -= tp; packed[v] = p; }         // deg -= seg*av (field-safe)
            tmp[v] = 0u;
        }
    }
    unsigned int c = p >> 16, pos = p & 0xFFFFu;
    bool nsv = av_new && (pos == 0u || pos == c);           // next single_v
    unsigned long long nsvb = __ballot(nsv);
    if (lane == 0 && valid) {
        svm[v >> 6] = nsvb;
        avm[v >> 6] = avw & ~svw;
    }
}

__global__ void k_out(const unsigned int* __restrict__ packed, float* __restrict__ deg) {
    int v = blockIdx.x * blockDim.x + threadIdx.x;
    if (v < Vn) deg[v] = (float)(packed[v] >> 16);
}

extern "C" void kernel_launch(void* const* d_in, const int* in_sizes, int n_in,
                              void* d_out, int out_size, void* d_ws, size_t ws_size,
                              hipStream_t stream) {
    const int*   graph_map        = (const int*)d_in[0];   // row0 = vidx
    const float* edge_feature     = (const float*)d_in[1];
    const float* active_variables = (const float*)d_in[2];
    const float* active_functions = (const float*)d_in[3];
    const int* vidx = graph_map;

    float* deg = (float*)d_out;
    char* ws = (char*)d_ws;
    size_t off = 0;
    unsigned long long* gpack = (unsigned long long*)(ws + off); off += 8ull * Fn;            // 33.6 MB
    unsigned int* packed      = (unsigned int*)(ws + off);       off += 4ull * Vn;            // 4.0 MB
    unsigned long long* avm   = (unsigned long long*)(ws + off); off += 8ull * (Vn / 64);     // 125 KB
    unsigned long long* svm   = (unsigned long long*)(ws + off); off += 8ull * (Vn / 64);     // 125 KB
    unsigned short* offs      = (unsigned short*)(ws + off);     off += 2ull * SBLK * OROW;   // 1.0 MB
    unsigned short* sorted    = (unsigned short*)(ws + off);     off += 2ull * SBLK * RSTRIDE;// 25.3 MB
    unsigned int* tmp = (unsigned int*)sorted;  // alias: tmp (4 MB) reuses sorted after k_accum
    // total ~64.2 MB

    const int BS = 256;
    const int gV = (Vn + BS - 1) / BS;
    const int gF = (Fn + BS - 1) / BS;

    k_pack_sort<<<SBLK, 512, 0, stream>>>(vidx, edge_feature, active_functions, gpack, offs, sorted);
    k_accum<<<NB, 512, 0, stream>>>(offs, sorted, active_variables, packed, avm, svm);
    k_zero_tmp<<<gV, BS, 0, stream>>>(tmp);
    for (int t = 0; t < Tn; ++t) {
        k_funcs<<<gF, BS, 0, stream>>>(gpack, (const unsigned int*)svm, tmp);
        k_update<<<gV, BS, 0, stream>>>(packed, tmp, avm, svm);
    }
    k_out<<<gV, BS, 0, stream>>>(packed, deg);
}